// Round 1
// baseline (7983.527 us; speedup 1.0000x reference)
//
#include <hip/hip_runtime.h>
#include <math.h>

#define E 8
#define S 6000
#define D 128
#define A 16
#define L 64
#define H 256
#define C 64
#define B 50
#define T 120
#define NSUB 2
#define FLAT 208      // L + A + D
#define RTOT 400      // E * B
#define RPB 4
#define NBLK (RTOT / RPB)

#define DT 0.5f
#define SQDT 0.70710678118654752440f

#define GNT 4096
#define GYMIN (-128.0f)
#define GDY 0.0625f
#define GINVDY 16.0f

__device__ __forceinline__ float sigf(float x) { return 1.0f / (1.0f + __expf(-x)); }

// ---------------------------------------------------------------- g table
__global__ void gtab_kernel(const float* __restrict__ gw1, const float* __restrict__ gb1,
                            const float* __restrict__ gw2, const float* __restrict__ gb2,
                            float* __restrict__ tab) {
    int idx = blockIdx.x * blockDim.x + threadIdx.x;
    if (idx >= L * GNT) return;
    int l = idx / GNT, i = idx % GNT;
    float y = GYMIN + (float)i * GDY;
    const float* w1 = gw1 + l * H;
    const float* b1 = gb1 + l * H;
    const float* w2 = gw2 + l * H;
    float acc = gb2[l];
    #pragma unroll 4
    for (int h = 0; h < H; ++h) acc += w2[h] * sigf(y * w1[h] + b1[h]);
    tab[idx] = acc;
}

// ---------------------------------------------------------------- encoder + KL (+ z0 at t=0)
__global__ void enc_kernel(const float* __restrict__ xs, const float* __restrict__ z0n,
                           const float* __restrict__ ew1, const float* __restrict__ eb1,
                           const float* __restrict__ ew2, const float* __restrict__ eb2,
                           const float* __restrict__ qw,  const float* __restrict__ qb,
                           const float* __restrict__ pm,  const float* __restrict__ pl,
                           float* __restrict__ z0buf, float* __restrict__ logqp0) {
    int bid = blockIdx.x;            // t*E + e
    int t = bid / E, e = bid % E;
    int tid = threadIdx.x;           // 256
    __shared__ float xsh[D], c1s[H], ctxs[C], qs[2 * L];
    float kl_acc = 0.0f;
    for (int b = 0; b < B; ++b) {
        const float* xrow = xs + ((size_t)e * S + (size_t)t * B + b) * D;
        if (tid < D) xsh[tid] = xrow[tid];
        __syncthreads();
        {   // c1 = sigmoid(x @ ew1 + eb1)
            float acc = eb1[e * H + tid];
            const float* w = ew1 + (size_t)e * D * H + tid;
            #pragma unroll 4
            for (int d = 0; d < D; ++d) acc += xsh[d] * w[(size_t)d * H];
            c1s[tid] = sigf(acc);
        }
        __syncthreads();
        if (tid < C) {   // ctx
            float acc = eb2[e * C + tid];
            const float* w = ew2 + (size_t)e * H * C + tid;
            #pragma unroll 4
            for (int h = 0; h < H; ++h) acc += c1s[h] * w[(size_t)h * C];
            ctxs[tid] = acc;
        }
        __syncthreads();
        if (tid < 2 * L) {   // q
            float acc = qb[e * 2 * L + tid];
            const float* w = qw + (size_t)e * C * 2 * L + tid;
            #pragma unroll 4
            for (int c = 0; c < C; ++c) acc += ctxs[c] * w[(size_t)c * 2 * L];
            qs[tid] = acc;
        }
        __syncthreads();
        if (t == 0 && tid < L) {
            float n = z0n[(((size_t)0 * E + e) * B + b) * L + tid];
            z0buf[((size_t)e * B + b) * L + tid] = qs[tid] + __expf(qs[L + tid]) * n;
        }
        if (tid < L) {
            float qm = qs[tid], ql = qs[L + tid];
            float m = pm[e * L + tid], ls = pl[e * L + tid];
            float dq = qm - m;
            float kl = ls - ql + (__expf(2.0f * ql) + dq * dq) / (2.0f * __expf(2.0f * ls)) - 0.5f;
            #pragma unroll
            for (int off = 32; off; off >>= 1) kl += __shfl_xor(kl, off);
            kl_acc += kl;
        }
        __syncthreads();
    }
    if (tid == 0) logqp0[t * E + e] = kl_acc / (float)B;
}

// ---------------------------------------------------------------- action/x part of z_enc
__global__ void ax_kernel(const float* __restrict__ xs, const float* __restrict__ actions,
                          const float* __restrict__ aw, const float* __restrict__ ab,
                          float* __restrict__ ax) {
    int bid = blockIdx.x;            // (t*E + e)*B + b
    int b = bid % B; int te = bid / B; int e = te % E; int t = te / E;
    int l = threadIdx.x;             // 64
    size_t row = (size_t)e * S + (size_t)t * B + b;
    float acc = ab[e * L + l];
    const float* awp = aw + ((size_t)e * FLAT + L) * L + l;
    const float* arow = actions + row * A;
    #pragma unroll 4
    for (int a = 0; a < A; ++a) acc += arow[a] * awp[(size_t)a * L];
    const float* xwp = aw + ((size_t)e * FLAT + L + A) * L + l;
    const float* xrow = xs + row * D;
    #pragma unroll 4
    for (int d = 0; d < D; ++d) acc += xrow[d] * xwp[(size_t)d * L];
    ax[(size_t)bid * L + l] = acc;
}

// ---------------------------------------------------------------- drift_all (device)
__device__ __forceinline__ void drift(
    const float (*y)[L],
    float (*fzo)[L], float (*gzo)[L], float* lfo,
    float (*h1f)[H], float (*h1h)[H], float (*h2f)[H], float (*h2h)[H],
    float (*cpf)[L], float (*cph)[L],
    const float* __restrict__ fw1, const float* __restrict__ fb1,
    const float* __restrict__ fw2, const float* __restrict__ fb2,
    const float* __restrict__ fw3, const float* __restrict__ fb3,
    const float* __restrict__ hw1, const float* __restrict__ hb1,
    const float* __restrict__ hw2, const float* __restrict__ hb2,
    const float* __restrict__ hw3, const float* __restrict__ hb3,
    const float* __restrict__ gtab, int tid)
{
    int h = tid & 255;
    int rp = tid >> 8;               // 0..1
    int r0 = rp * 2, r1 = rp * 2 + 1;
    {   // stage a: (RPB,64) @ (64,256) for f and h nets
        float af0 = fb1[h], af1 = af0, ah0 = hb1[h], ah1 = ah0;
        const float* wf = fw1 + h;
        const float* wh = hw1 + h;
        #pragma unroll 4
        for (int k = 0; k < L; ++k) {
            float wfv = wf[k * H], whv = wh[k * H];
            float y0 = y[r0][k], y1 = y[r1][k];
            af0 += y0 * wfv; af1 += y1 * wfv;
            ah0 += y0 * whv; ah1 += y1 * whv;
        }
        h1f[r0][h] = sigf(af0); h1f[r1][h] = sigf(af1);
        h1h[r0][h] = sigf(ah0); h1h[r1][h] = sigf(ah1);
    }
    __syncthreads();
    {   // stage b: (RPB,256) @ (256,256)
        float af0 = fb2[h], af1 = af0, ah0 = hb2[h], ah1 = ah0;
        const float* wf = fw2 + h;
        const float* wh = hw2 + h;
        #pragma unroll 4
        for (int k = 0; k < H; ++k) {
            float wfv = wf[k * H], whv = wh[k * H];
            af0 += h1f[r0][k] * wfv; af1 += h1f[r1][k] * wfv;
            ah0 += h1h[r0][k] * whv; ah1 += h1h[r1][k] * whv;
        }
        h2f[r0][h] = sigf(af0); h2f[r1][h] = sigf(af1);
        h2h[r0][h] = sigf(ah0); h2h[r1][h] = sigf(ah1);
    }
    __syncthreads();
    {   // stage c: (RPB,256) @ (256,64) for f,h + gz table + lf
        int l = tid & 63;
        int row = (tid >> 6) & 3;
        int kh = tid >> 8;           // k-half
        float accf = 0.0f, acch = 0.0f;
        const float* wf = fw3 + l;
        const float* wh = hw3 + l;
        int k0 = kh * 128;
        #pragma unroll 4
        for (int k = k0; k < k0 + 128; ++k) {
            accf += h2f[row][k] * wf[k * L];
            acch += h2h[row][k] * wh[k * L];
        }
        if (kh == 1) { cpf[row][l] = accf; cph[row][l] = acch; }
        __syncthreads();
        if (kh == 0) {
            float fv = accf + cpf[row][l] + fb3[l];
            float hv = acch + cph[row][l] + hb3[l];
            float yl = y[row][l];
            float x = (yl - GYMIN) * GINVDY;
            x = fminf(fmaxf(x, 0.0f), (float)(GNT - 2) + 0.999f);
            int i = (int)x;
            float fr = x - (float)i;
            const float* tl = gtab + (size_t)l * GNT;
            float gv = tl[i] * (1.0f - fr) + tl[i + 1] * fr;
            float u = (fv - hv) / gv;
            fzo[row][l] = fv;
            gzo[row][l] = gv;
            float us = u * u;
            #pragma unroll
            for (int off = 32; off; off >>= 1) us += __shfl_xor(us, off);
            if (l == 0) lfo[row] = 0.5f * us;
        }
        __syncthreads();
    }
}

// ---------------------------------------------------------------- sequential SDE loop
__global__ __launch_bounds__(512) void seq_kernel(
    const float* __restrict__ aw, const float* __restrict__ dW,
    const float* __restrict__ z0buf, const float* __restrict__ axbuf,
    const float* __restrict__ fw1, const float* __restrict__ fb1,
    const float* __restrict__ fw2, const float* __restrict__ fb2,
    const float* __restrict__ fw3, const float* __restrict__ fb3,
    const float* __restrict__ hw1, const float* __restrict__ hb1,
    const float* __restrict__ hw2, const float* __restrict__ hb2,
    const float* __restrict__ hw3, const float* __restrict__ hb3,
    const float* __restrict__ gtab, float* __restrict__ z_all, float* __restrict__ rowlr)
{
    __shared__ float Z[RPB][L];
    __shared__ float zc[RPB][L], zhA[RPB][L], zhB[RPB][L], dwS[RPB][L];
    __shared__ float fzb[2][RPB][L], gzb[2][RPB][L];
    __shared__ float lfb[2][RPB], lcS[RPB], lrsum[RPB];
    __shared__ float h1f[RPB][H], h1h[RPB][H], h2f[RPB][H], h2h[RPB][H];
    __shared__ float cpf[RPB][L], cph[RPB][L];

    int tid = threadIdx.x;
    int r_base = blockIdx.x * RPB;
    int row = (tid >> 6) & 3;
    int l = tid & 63;
    int r_glob = r_base + row;
    int e_row = r_glob / B;
    int b_row = r_glob % B;

    if (tid < 256) Z[row][l] = z0buf[(size_t)r_glob * L + l];
    if (tid < RPB) lrsum[tid] = 0.0f;
    __syncthreads();

    for (int t = 0; t < T; ++t) {
        // z_enc = z_in @ act_w[:, :L] + (precomputed action/x part)
        if (tid < 256) {
            float acc = axbuf[((((size_t)t * E + e_row) * B) + b_row) * L + l];
            const float* w = aw + ((size_t)e_row * FLAT) * L + l;
            #pragma unroll 4
            for (int k = 0; k < L; ++k) acc += Z[row][k] * w[k * L];
            zc[row][l] = acc;
            zhA[row][l] = acc;   // zh init = zini
        }
        if (tid < RPB) lcS[tid] = 0.0f;
        __syncthreads();

        drift(zc, fzb[0], gzb[0], lfb[0], h1f, h1h, h2f, h2h, cpf, cph,
              fw1, fb1, fw2, fb2, fw3, fb3, hw1, hb1, hw2, hb2, hw3, hb3, gtab, tid);

        int cur = 0;
        float (*zh)[L] = zhA;
        float (*zt)[L] = zhB;
        #pragma unroll
        for (int k = 0; k < NSUB; ++k) {
            int nxt = cur ^ 1;
            if (tid < 256) {
                float dwv = dW[(((size_t)t * NSUB + k) * RTOT + r_glob) * L + l] * SQDT;
                dwS[row][l] = dwv;
                zt[row][l] = 2.0f * zc[row][l] - zh[row][l]
                           + fzb[cur][row][l] * DT + gzb[cur][row][l] * dwv;
            }
            __syncthreads();
            drift(zt, fzb[nxt], gzb[nxt], lfb[nxt], h1f, h1h, h2f, h2h, cpf, cph,
                  fw1, fb1, fw2, fb2, fw3, fb3, hw1, hb1, hw2, hb2, hw3, hb3, gtab, tid);
            if (tid < 256) {
                zc[row][l] += 0.5f * (fzb[cur][row][l] + fzb[nxt][row][l]) * DT
                            + 0.5f * (gzb[cur][row][l] + gzb[nxt][row][l]) * dwS[row][l];
            }
            if (tid < RPB) lcS[tid] += 0.5f * (lfb[cur][tid] + lfb[nxt][tid]) * DT;
            { float (*tmp)[L] = zh; zh = zt; zt = tmp; }
            cur = nxt;
            __syncthreads();
        }
        if (tid < 256) {
            Z[row][l] = zc[row][l];
            z_all[((size_t)t * RTOT + r_glob) * L + l] = zc[row][l];
        }
        if (tid < RPB) lrsum[tid] += lcS[tid];
        __syncthreads();
    }
    if (tid < RPB) rowlr[r_base + tid] = lrsum[tid];
}

// ---------------------------------------------------------------- projection
__global__ void proj_kernel(const float* __restrict__ z_all,
                            const float* __restrict__ pw1, const float* __restrict__ pb1,
                            const float* __restrict__ pw2, const float* __restrict__ pb2,
                            const float* __restrict__ pw3, const float* __restrict__ pb3,
                            float* __restrict__ out) {
    int bid = blockIdx.x;            // t*E + e
    int t = bid / E, e = bid % E;
    int tid = threadIdx.x;           // 256
    __shared__ float zs[L], p1s[H], p2s[H];
    for (int b = 0; b < B; ++b) {
        int r = e * B + b;
        if (tid < L) zs[tid] = z_all[((size_t)t * RTOT + r) * L + tid];
        __syncthreads();
        {
            float acc = pb1[e * H + tid];
            const float* w = pw1 + (size_t)e * L * H + tid;
            #pragma unroll 4
            for (int k = 0; k < L; ++k) acc += zs[k] * w[(size_t)k * H];
            p1s[tid] = sigf(acc);
        }
        __syncthreads();
        {
            float acc = pb2[e * H + tid];
            const float* w = pw2 + (size_t)e * H * H + tid;
            #pragma unroll 4
            for (int k = 0; k < H; ++k) acc += p1s[k] * w[(size_t)k * H];
            p2s[tid] = sigf(acc);
        }
        __syncthreads();
        if (tid < D) {
            float acc = pb3[e * D + tid];
            const float* w = pw3 + (size_t)e * H * D + tid;
            #pragma unroll 4
            for (int k = 0; k < H; ++k) acc += p2s[k] * w[(size_t)k * D];
            out[8 + ((size_t)e * S + (size_t)t * B + b) * D + tid] = acc;
        }
        __syncthreads();
    }
}

// ---------------------------------------------------------------- final combine
__global__ void fin_kernel(const float* __restrict__ logqp0, const float* __restrict__ rowlr,
                           float* __restrict__ out) {
    int e = threadIdx.x;
    if (e < E) {
        float acc = 0.0f;
        for (int t = 0; t < T; ++t) acc += logqp0[t * E + e];
        float s = 0.0f;
        for (int b = 0; b < B; ++b) s += rowlr[e * B + b];
        out[e] = acc + s / (float)B;
    }
}

extern "C" void kernel_launch(void* const* d_in, const int* in_sizes, int n_in,
                              void* d_out, int out_size, void* d_ws, size_t ws_size,
                              hipStream_t stream) {
    const float* xs      = (const float*)d_in[0];
    const float* actions = (const float*)d_in[1];
    const float* z0n     = (const float*)d_in[2];
    const float* dWp     = (const float*)d_in[3];
    const float* ew1     = (const float*)d_in[4];
    const float* eb1     = (const float*)d_in[5];
    const float* ew2     = (const float*)d_in[6];
    const float* eb2     = (const float*)d_in[7];
    const float* qw      = (const float*)d_in[8];
    const float* qb      = (const float*)d_in[9];
    const float* aw      = (const float*)d_in[10];
    const float* ab      = (const float*)d_in[11];
    const float* fw1     = (const float*)d_in[12];
    const float* fb1     = (const float*)d_in[13];
    const float* fw2     = (const float*)d_in[14];
    const float* fb2     = (const float*)d_in[15];
    const float* fw3     = (const float*)d_in[16];
    const float* fb3     = (const float*)d_in[17];
    const float* hw1     = (const float*)d_in[18];
    const float* hb1     = (const float*)d_in[19];
    const float* hw2     = (const float*)d_in[20];
    const float* hb2     = (const float*)d_in[21];
    const float* hw3     = (const float*)d_in[22];
    const float* hb3     = (const float*)d_in[23];
    const float* gw1     = (const float*)d_in[24];
    const float* gb1     = (const float*)d_in[25];
    const float* gw2     = (const float*)d_in[26];
    const float* gb2     = (const float*)d_in[27];
    const float* pw1     = (const float*)d_in[28];
    const float* pb1     = (const float*)d_in[29];
    const float* pw2     = (const float*)d_in[30];
    const float* pb2     = (const float*)d_in[31];
    const float* pw3     = (const float*)d_in[32];
    const float* pb3     = (const float*)d_in[33];
    const float* pm      = (const float*)d_in[34];
    const float* pl      = (const float*)d_in[35];

    float* ws      = (float*)d_ws;
    float* z0buf   = ws;                       // E*B*L            = 25600
    float* axbuf   = z0buf + 25600;            // T*E*B*L          = 3072000
    float* z_all   = axbuf + 3072000;          // T*RTOT*L         = 3072000
    float* logqp0  = z_all + 3072000;          // T*E              = 960
    float* rowlr   = logqp0 + 960;             // RTOT             = 400
    float* gtab    = rowlr + 400;              // L*GNT            = 262144
    float* out     = (float*)d_out;

    gtab_kernel<<<(L * GNT + 255) / 256, 256, 0, stream>>>(gw1, gb1, gw2, gb2, gtab);
    enc_kernel<<<T * E, 256, 0, stream>>>(xs, z0n, ew1, eb1, ew2, eb2, qw, qb, pm, pl, z0buf, logqp0);
    ax_kernel<<<T * E * B, 64, 0, stream>>>(xs, actions, aw, ab, axbuf);
    seq_kernel<<<NBLK, 512, 0, stream>>>(aw, dWp, z0buf, axbuf,
                                         fw1, fb1, fw2, fb2, fw3, fb3,
                                         hw1, hb1, hw2, hb2, hw3, hb3,
                                         gtab, z_all, rowlr);
    proj_kernel<<<T * E, 256, 0, stream>>>(z_all, pw1, pb1, pw2, pb2, pw3, pb3, out);
    fin_kernel<<<1, 64, 0, stream>>>(logqp0, rowlr, out);
}